// Round 1
// baseline (130.960 us; speedup 1.0000x reference)
//
#include <hip/hip_runtime.h>
#include <hip/hip_bf16.h>

// CombinedRotaryEmbedding: fold Givens chain + rotation_matrix into one 64x64
// matrix (prep kernel), then y = x_row @ Mt with RoPE epilogue (main kernel).
//
// Mt layout: row c (64 floats, contiguous) = the M column that produces output
// component c AFTER the even/odd permutation:
//   c in [0,32):  original column 2c      (the "x1" components)
//   c in [32,64): original column 2(c-32)+1  (the "x2" components)
// Then out[c] = y[c]*cos(f) + partner*(c<32 ? -sin : +sin), partner = shfl_xor(y,32).

#define S_LEN 8192
#define TOKENS_PER_WAVE 2

typedef __attribute__((ext_vector_type(16))) float f32x16;

__global__ __launch_bounds__(64) void prep_kernel(
    const float* __restrict__ thetas,
    const float* __restrict__ R,
    float* __restrict__ Mt) {
  const int t = threadIdx.x;  // original column index 0..63
  float col[64];
#pragma unroll
  for (int d = 0; d < 64; ++d) col[d] = R[d * 64 + t];
  // M = G0 G1 ... G31 R ; left-multiply by Gk updates rows k, k+1:
  //   new_row_k   =  c*row_k - s*row_{k+1}
  //   new_row_k+1 =  s*row_k + c*row_{k+1}
  // Apply k = 31 down to 0. Thread t holds column t, so row ops are local.
#pragma unroll
  for (int k = 31; k >= 0; --k) {
    float th = thetas[k];
    float ck = cosf(th), sk = sinf(th);
    float a = col[k], b = col[k + 1];
    col[k]     = ck * a - sk * b;
    col[k + 1] = sk * a + ck * b;
  }
  const int p = (t & 1) ? (32 + (t >> 1)) : (t >> 1);
#pragma unroll
  for (int d = 0; d < 64; ++d) Mt[p * 64 + d] = col[d];
}

__global__ __launch_bounds__(256) void rope_main(
    const float* __restrict__ x,
    const float* __restrict__ inv_freq,
    const float* __restrict__ Mt,
    float* __restrict__ out) {
  const int lane = threadIdx.x & 63;
  int gw = (int)blockIdx.x * 4 + (int)(threadIdx.x >> 6);
  gw = __builtin_amdgcn_readfirstlane(gw);  // wave-uniform

  const int c = lane;
  // Load this lane's M column (row c of Mt) into 64 VGPRs.
  float m[64];
  const float4* mt4 = (const float4*)(Mt + c * 64);
#pragma unroll
  for (int i = 0; i < 16; ++i) {
    float4 v = mt4[i];
    m[4 * i + 0] = v.x;
    m[4 * i + 1] = v.y;
    m[4 * i + 2] = v.z;
    m[4 * i + 3] = v.w;
  }

  const int f = c & 31;
  const float ivf = inv_freq[f];

#pragma unroll 1
  for (int t = 0; t < TOKENS_PER_WAVE; ++t) {
    const int tk = gw * TOKENS_PER_WAVE + t;  // token id, 0..B*S-1
    const int pos = tk & (S_LEN - 1);         // position within sequence
    float sv, cv;
    sincosf((float)pos * ivf, &sv, &cv);
    const float sc = (c < 32) ? -sv : sv;

    const float* xrow0 = x + (size_t)tk * 1024;
    float* orow0 = out + (size_t)tk * 1024;

#pragma unroll 1
    for (int r = 0; r < 16; ++r) {
      const float* xrow = xrow0 + r * 64;
      f32x16 a0, a1, a2, a3;
      asm volatile(
          "s_load_dwordx16 %0, %4, 0x0\n\t"
          "s_load_dwordx16 %1, %4, 0x40\n\t"
          "s_load_dwordx16 %2, %4, 0x80\n\t"
          "s_load_dwordx16 %3, %4, 0xc0\n\t"
          "s_waitcnt lgkmcnt(0)"
          : "=&s"(a0), "=&s"(a1), "=&s"(a2), "=&s"(a3)
          : "s"(xrow));
      float y0 = 0.f, y1 = 0.f, y2 = 0.f, y3 = 0.f;
#pragma unroll
      for (int d = 0; d < 16; ++d) {
        y0 = fmaf(a0[d], m[d], y0);
        y1 = fmaf(a1[d], m[16 + d], y1);
        y2 = fmaf(a2[d], m[32 + d], y2);
        y3 = fmaf(a3[d], m[48 + d], y3);
      }
      float y = (y0 + y1) + (y2 + y3);
      float pr = __shfl_xor(y, 32);
      orow0[r * 64 + c] = fmaf(pr, sc, y * cv);
    }
  }
}

extern "C" void kernel_launch(void* const* d_in, const int* in_sizes, int n_in,
                              void* d_out, int out_size, void* d_ws, size_t ws_size,
                              hipStream_t stream) {
  const float* x        = (const float*)d_in[0];
  const float* thetas   = (const float*)d_in[1];
  const float* R        = (const float*)d_in[2];
  const float* inv_freq = (const float*)d_in[3];
  float* Mt = (float*)d_ws;  // 64*64*4 = 16 KB scratch

  prep_kernel<<<1, 64, 0, stream>>>(thetas, R, Mt);

  // B*S = 32768 tokens; 1 wave handles TOKENS_PER_WAVE tokens (16 rows each).
  // waves = 32768 / 2 = 16384; blocks (4 waves each) = 4096.
  rope_main<<<4096, 256, 0, stream>>>(x, inv_freq, Mt, (float*)d_out);
}

// Round 2
// 61.364 us; speedup vs baseline: 2.1341x; 2.1341x over previous
//
#include <hip/hip_runtime.h>
#include <hip/hip_bf16.h>

// CombinedRotaryEmbedding via MFMA.
// Step 1 (prep, 1 wave): fold Givens chain into rotation_matrix -> M (64x64),
//   apply the RoPE even/odd column permutation, split into bf16 hi/lo, and
//   store as ready-to-load mfma_f32_16x16x32_bf16 B-fragments in d_ws.
// Step 2 (main): per wave, 16 consecutive head-rows (= all 16 heads of ONE
//   token) form the A tile (16x64). Y = Ahi*Bhi + Alo*Bhi + Ahi*Blo (3-term
//   bf16 split ~ fp32 accuracy). Epilogue applies RoPE: all rows in a tile
//   share one position, so only 2 sincosf per lane per tile.
//
// Assumed fragment mappings (16x16x32 bf16):
//   A: row = lane&15, k = (lane>>4)*8 + e   (e = 0..7)
//   B: col = lane&15, k = (lane>>4)*8 + e
//   D: col = lane&15, row = (lane>>4)*4 + reg   [HW-verified, learn_hip m89]
// Any error in the k-mapping guess is applied identically to A and B and
// cancels in the contraction.

#define TILES_PER_WAVE 8
#define N_ROWS (4 * 8192 * 16)         // B*S*n_head head-rows of 64
#define N_TILES (N_ROWS / 16)          // 32768
#define N_WAVES (N_TILES / TILES_PER_WAVE)
#define N_BLOCKS (N_WAVES / 4)

typedef __attribute__((ext_vector_type(8))) short short8;
typedef __attribute__((ext_vector_type(4))) float f32x4;

__device__ __forceinline__ unsigned short f2bf(float f) {
  unsigned int u = __float_as_uint(f);
  u += 0x7fff + ((u >> 16) & 1);  // RNE
  return (unsigned short)(u >> 16);
}
__device__ __forceinline__ float bf2f(unsigned short h) {
  return __uint_as_float(((unsigned int)h) << 16);
}

__global__ __launch_bounds__(64) void prep_kernel(
    const float* __restrict__ thetas,
    const float* __restrict__ R,
    short* __restrict__ Bws) {
  const int t = threadIdx.x;  // 0..63
  // Column t of M = (G0 G1 ... G31) R. Givens Gk mixes ROWS k,k+1 -> lane-local.
  float col[64];
#pragma unroll
  for (int d = 0; d < 64; ++d) col[d] = R[d * 64 + t];
#pragma unroll
  for (int k = 31; k >= 0; --k) {
    float th = thetas[k];
    float ck = cosf(th), sk = sinf(th);
    float a = col[k], b = col[k + 1];
    col[k]     = ck * a - sk * b;
    col[k + 1] = sk * a + ck * b;
  }
  __shared__ float Ml[64][64];  // Ml[d][c] = M[d][c]
#pragma unroll
  for (int d = 0; d < 64; ++d) Ml[d][t] = col[d];
  __syncthreads();

  // Build B fragments. Output col c' (after RoPE permutation):
  //   c' < 32  -> original col 2c'   ; c' >= 32 -> original col 2(c'-32)+1
  short8* Bp = (short8*)Bws;
  const int cb = t & 15, kg = t >> 4;
#pragma unroll
  for (int s = 0; s < 2; ++s) {
#pragma unroll
    for (int nt = 0; nt < 4; ++nt) {
      const int c2 = cb + 16 * nt;
      const int pc = (c2 < 32) ? (2 * c2) : (2 * (c2 - 32) + 1);
      short8 hf, lf;
#pragma unroll
      for (int e = 0; e < 8; ++e) {
        const int k = s * 32 + kg * 8 + e;
        float m = Ml[k][pc];
        unsigned short hi = f2bf(m);
        unsigned short lo = f2bf(m - bf2f(hi));
        hf[e] = (short)hi;
        lf[e] = (short)lo;
      }
      Bp[(s * 4 + nt) * 64 + t] = hf;        // hi frags: idx 0..7
      Bp[(8 + s * 4 + nt) * 64 + t] = lf;    // lo frags: idx 8..15
    }
  }
}

__global__ __launch_bounds__(256) void rope_mfma(
    const float* __restrict__ x,
    const float* __restrict__ inv_freq,
    const short* __restrict__ Bws,
    float* __restrict__ out) {
  const int lane = threadIdx.x & 63;
  const int wave = (int)blockIdx.x * 4 + (int)(threadIdx.x >> 6);
  const int cb = lane & 15;   // col within 16-tile / A row within tile
  const int kg = lane >> 4;   // k-group

  // Load B fragments (16 KB shared by all waves -> L2 resident).
  const short8* Bp = (const short8*)Bws;
  short8 bh[8], bl[8];  // idx = s*4 + nt
#pragma unroll
  for (int i = 0; i < 8; ++i) {
    bh[i] = Bp[i * 64 + lane];
    bl[i] = Bp[(8 + i) * 64 + lane];
  }

  const float ivf0 = inv_freq[cb];
  const float ivf1 = inv_freq[cb + 16];

#pragma unroll 1
  for (int t = 0; t < TILES_PER_WAVE; ++t) {
    const int tile = wave * TILES_PER_WAVE + t;   // == token index
    const size_t rb = (size_t)tile * 16;          // first head-row of tile

    // A tile: row (lane&15) of the 16 rows, k = s*32 + kg*8 + e.
    const float4* xr = (const float4*)(x + (rb + cb) * 64 + kg * 8);
    float4 q0 = xr[0], q1 = xr[1];   // s = 0
    float4 q2 = xr[8], q3 = xr[9];   // s = 1 (+32 floats)

    short8 ah[2], al[2];
    {
      const float* qs[2][2] = {{(float*)&q0, (float*)&q1}, {(float*)&q2, (float*)&q3}};
#pragma unroll
      for (int s = 0; s < 2; ++s) {
#pragma unroll
        for (int e = 0; e < 8; ++e) {
          float f = qs[s][e >> 2][e & 3];
          unsigned short hi = f2bf(f);
          unsigned short lo = f2bf(f - bf2f(hi));
          ah[s][e] = (short)hi;
          al[s][e] = (short)lo;
        }
      }
    }

    f32x4 acc[4];
#pragma unroll
    for (int nt = 0; nt < 4; ++nt) acc[nt] = (f32x4){0.f, 0.f, 0.f, 0.f};
#pragma unroll
    for (int s = 0; s < 2; ++s) {
#pragma unroll
      for (int nt = 0; nt < 4; ++nt) {
        acc[nt] = __builtin_amdgcn_mfma_f32_16x16x32_bf16(ah[s], bh[s * 4 + nt], acc[nt], 0, 0, 0);
        acc[nt] = __builtin_amdgcn_mfma_f32_16x16x32_bf16(al[s], bh[s * 4 + nt], acc[nt], 0, 0, 0);
        acc[nt] = __builtin_amdgcn_mfma_f32_16x16x32_bf16(ah[s], bl[s * 4 + nt], acc[nt], 0, 0, 0);
      }
    }

    // RoPE epilogue. All 16 rows of this tile share position = tile % 8192.
    const int pos = tile & 8191;
    float sv0, cv0, sv1, cv1;
    sincosf((float)pos * ivf0, &sv0, &cv0);
    sincosf((float)pos * ivf1, &sv1, &cv1);

    float* orow = out + rb * 64;
#pragma unroll
    for (int nt = 0; nt < 4; ++nt) {
      const float cvx = (nt & 1) ? cv1 : cv0;
      const float ssv = ((nt & 1) ? sv1 : sv0) * ((nt < 2) ? -1.f : 1.f);
#pragma unroll
      for (int r = 0; r < 4; ++r) {
        float y = acc[nt][r];
        float p = acc[nt ^ 2][r];
        orow[(kg * 4 + r) * 64 + cb + 16 * nt] = fmaf(p, ssv, y * cvx);
      }
    }
  }
}

extern "C" void kernel_launch(void* const* d_in, const int* in_sizes, int n_in,
                              void* d_out, int out_size, void* d_ws, size_t ws_size,
                              hipStream_t stream) {
  const float* x        = (const float*)d_in[0];
  const float* thetas   = (const float*)d_in[1];
  const float* R        = (const float*)d_in[2];
  const float* inv_freq = (const float*)d_in[3];

  prep_kernel<<<1, 64, 0, stream>>>(thetas, R, (short*)d_ws);
  rope_mfma<<<N_BLOCKS, 256, 0, stream>>>(x, inv_freq, (const short*)d_ws, (float*)d_out);
}

// Round 3
// 61.081 us; speedup vs baseline: 2.1440x; 1.0046x over previous
//
#include <hip/hip_runtime.h>
#include <hip/hip_bf16.h>

// CombinedRotaryEmbedding via MFMA.
// prep (1 wave): fold Givens chain into rotation_matrix -> M (64x64), apply
//   RoPE even/odd column permutation, split into bf16 hi/lo, store as
//   mfma_f32_16x16x32_bf16 B-fragments in d_ws.
// main: per wave, 16 head-rows of ONE token = 16x64 A tile.
//   Y = Ahi*Bhi + Alo*Bhi + Ahi*Blo (3-term bf16 split ~ fp32 accuracy).
//   Epilogue RoPE: one position per tile -> 2 __sincosf per lane per tile.
// TILES_PER_WAVE=2 -> 4096 blocks (64 waves/CU demanded) to hide HBM latency.

#define TILES_PER_WAVE 2
#define N_ROWS (4 * 8192 * 16)         // B*S*n_head head-rows of 64
#define N_TILES (N_ROWS / 16)          // 32768
#define N_WAVES (N_TILES / TILES_PER_WAVE)
#define N_BLOCKS (N_WAVES / 4)

typedef __attribute__((ext_vector_type(8))) short short8;
typedef __attribute__((ext_vector_type(4))) float f32x4;

__device__ __forceinline__ unsigned short f2bf(float f) {
  unsigned int u = __float_as_uint(f);
  u += 0x7fff + ((u >> 16) & 1);  // RNE
  return (unsigned short)(u >> 16);
}
__device__ __forceinline__ float bf2f(unsigned short h) {
  return __uint_as_float(((unsigned int)h) << 16);
}

__global__ __launch_bounds__(64) void prep_kernel(
    const float* __restrict__ thetas,
    const float* __restrict__ R,
    short* __restrict__ Bws) {
  const int t = threadIdx.x;  // 0..63
  float col[64];
#pragma unroll
  for (int d = 0; d < 64; ++d) col[d] = R[d * 64 + t];
#pragma unroll
  for (int k = 31; k >= 0; --k) {
    float th = thetas[k];
    float ck = cosf(th), sk = sinf(th);
    float a = col[k], b = col[k + 1];
    col[k]     = ck * a - sk * b;
    col[k + 1] = sk * a + ck * b;
  }
  __shared__ float Ml[64][64];
#pragma unroll
  for (int d = 0; d < 64; ++d) Ml[d][t] = col[d];
  __syncthreads();

  short8* Bp = (short8*)Bws;
  const int cb = t & 15, kg = t >> 4;
#pragma unroll
  for (int s = 0; s < 2; ++s) {
#pragma unroll
    for (int nt = 0; nt < 4; ++nt) {
      const int c2 = cb + 16 * nt;
      const int pc = (c2 < 32) ? (2 * c2) : (2 * (c2 - 32) + 1);
      short8 hf, lf;
#pragma unroll
      for (int e = 0; e < 8; ++e) {
        const int k = s * 32 + kg * 8 + e;
        float m = Ml[k][pc];
        unsigned short hi = f2bf(m);
        unsigned short lo = f2bf(m - bf2f(hi));
        hf[e] = (short)hi;
        lf[e] = (short)lo;
      }
      Bp[(s * 4 + nt) * 64 + t] = hf;        // hi frags: idx 0..7
      Bp[(8 + s * 4 + nt) * 64 + t] = lf;    // lo frags: idx 8..15
    }
  }
}

__global__ __launch_bounds__(256) void rope_mfma(
    const float* __restrict__ x,
    const float* __restrict__ inv_freq,
    const short* __restrict__ Bws,
    float* __restrict__ out) {
  const int lane = threadIdx.x & 63;
  const int wave = (int)blockIdx.x * 4 + (int)(threadIdx.x >> 6);
  const int cb = lane & 15;   // A row within tile / D col within 16-block
  const int kg = lane >> 4;   // k-group

  const short8* Bp = (const short8*)Bws;
  short8 bh[8], bl[8];  // idx = s*4 + nt; 16 KB table -> L2 resident
#pragma unroll
  for (int i = 0; i < 8; ++i) {
    bh[i] = Bp[i * 64 + lane];
    bl[i] = Bp[(8 + i) * 64 + lane];
  }

  const float ivf0 = inv_freq[cb];
  const float ivf1 = inv_freq[cb + 16];

#pragma unroll 1
  for (int t = 0; t < TILES_PER_WAVE; ++t) {
    const int tile = wave * TILES_PER_WAVE + t;   // == token index
    const size_t rb = (size_t)tile * 16;          // first head-row of tile

    const float4* xr = (const float4*)(x + (rb + cb) * 64 + kg * 8);
    float4 q0 = xr[0], q1 = xr[1];   // s = 0
    float4 q2 = xr[8], q3 = xr[9];   // s = 1 (+32 floats)

    short8 ah[2], al[2];
    {
      const float* qs[2][2] = {{(float*)&q0, (float*)&q1}, {(float*)&q2, (float*)&q3}};
#pragma unroll
      for (int s = 0; s < 2; ++s) {
#pragma unroll
        for (int e = 0; e < 8; ++e) {
          float f = qs[s][e >> 2][e & 3];
          unsigned short hi = f2bf(f);
          unsigned short lo = f2bf(f - bf2f(hi));
          ah[s][e] = (short)hi;
          al[s][e] = (short)lo;
        }
      }
    }

    f32x4 acc[4];
#pragma unroll
    for (int nt = 0; nt < 4; ++nt) acc[nt] = (f32x4){0.f, 0.f, 0.f, 0.f};
#pragma unroll
    for (int s = 0; s < 2; ++s) {
#pragma unroll
      for (int nt = 0; nt < 4; ++nt) {
        acc[nt] = __builtin_amdgcn_mfma_f32_16x16x32_bf16(ah[s], bh[s * 4 + nt], acc[nt], 0, 0, 0);
        acc[nt] = __builtin_amdgcn_mfma_f32_16x16x32_bf16(al[s], bh[s * 4 + nt], acc[nt], 0, 0, 0);
        acc[nt] = __builtin_amdgcn_mfma_f32_16x16x32_bf16(ah[s], bl[s * 4 + nt], acc[nt], 0, 0, 0);
      }
    }

    // RoPE epilogue; position = tile % 8192 shared by all 16 rows.
    const int pos = tile & 8191;
    float sv0, cv0, sv1, cv1;
    __sincosf((float)pos * ivf0, &sv0, &cv0);
    __sincosf((float)pos * ivf1, &sv1, &cv1);

    float* orow = out + rb * 64;
#pragma unroll
    for (int nt = 0; nt < 4; ++nt) {
      const float cvx = (nt & 1) ? cv1 : cv0;
      const float ssv = ((nt & 1) ? sv1 : sv0) * ((nt < 2) ? -1.f : 1.f);
#pragma unroll
      for (int r = 0; r < 4; ++r) {
        float y = acc[nt][r];
        float p = acc[nt ^ 2][r];
        orow[(kg * 4 + r) * 64 + cb + 16 * nt] = fmaf(p, ssv, y * cvx);
      }
    }
  }
}

extern "C" void kernel_launch(void* const* d_in, const int* in_sizes, int n_in,
                              void* d_out, int out_size, void* d_ws, size_t ws_size,
                              hipStream_t stream) {
  const float* x        = (const float*)d_in[0];
  const float* thetas   = (const float*)d_in[1];
  const float* R        = (const float*)d_in[2];
  const float* inv_freq = (const float*)d_in[3];

  prep_kernel<<<1, 64, 0, stream>>>(thetas, R, (short*)d_ws);
  rope_mfma<<<N_BLOCKS, 256, 0, stream>>>(x, inv_freq, (const short*)d_ws, (float*)d_out);
}